// Round 3
// baseline (107.847 us; speedup 1.0000x reference)
//
#include <hip/hip_runtime.h>

// Problem constants (fixed by reference: B=32,D=64,H=32,W=32,K=2048)
#define N_PIX 32768   // B*H*W
#define DIM   64
#define KCODE 2048

typedef __attribute__((ext_vector_type(8))) short bf16x8;   // 8 bf16 = 4 VGPR
typedef __attribute__((ext_vector_type(4))) float f32x4;    // MFMA C/D

// bf16 round-to-nearest-even (manual, deterministic)
__device__ inline unsigned short f2bf(float v) {
    unsigned int u = __float_as_uint(v);
    return (unsigned short)((u + 0x7FFFu + ((u >> 16) & 1u)) >> 16);
}
__device__ inline float bf2f(unsigned short b) {
    return __uint_as_float(((unsigned int)b) << 16);
}

// ---------------------------------------------------------------------------
// convert_b v2 (UNCHANGED): 16 threads/code, 128 blocks. One coalesced float4
// load per thread, split to 3 bf16 planes, e_sq via width-16 shfl butterfly.
// ---------------------------------------------------------------------------
__global__ __launch_bounds__(256)
void convert_b_kernel(const float* __restrict__ cb, unsigned short* __restrict__ Bg,
                      float* __restrict__ esq) {
    const int t   = blockIdx.x * 256 + threadIdx.x;   // 32768 threads
    const int n   = t >> 4;                           // code id 0..2047
    const int sub = t & 15;                           // 16 thr per code
    const int ntile = n >> 4, ni = n & 15;

    const float4 v = *(const float4*)(cb + (size_t)n * DIM + sub * 4);  // coalesced

    unsigned int h01, h23, m01, m23, l01, l23;
    {
        unsigned short h, m, l;
        float r1;
        h = f2bf(v.x); r1 = v.x - bf2f(h); m = f2bf(r1); l = f2bf(r1 - bf2f(m));
        h01 = h;       m01 = m;       l01 = l;
        h = f2bf(v.y); r1 = v.y - bf2f(h); m = f2bf(r1); l = f2bf(r1 - bf2f(m));
        h01 |= (unsigned int)h << 16; m01 |= (unsigned int)m << 16; l01 |= (unsigned int)l << 16;
        h = f2bf(v.z); r1 = v.z - bf2f(h); m = f2bf(r1); l = f2bf(r1 - bf2f(m));
        h23 = h;       m23 = m;       l23 = l;
        h = f2bf(v.w); r1 = v.w - bf2f(h); m = f2bf(r1); l = f2bf(r1 - bf2f(m));
        h23 |= (unsigned int)h << 16; m23 |= (unsigned int)m << 16; l23 |= (unsigned int)l << 16;
    }

    // e_sq: per-thread partial then width-16 butterfly (pairwise order)
    float s = (v.x * v.x + v.y * v.y) + (v.z * v.z + v.w * v.w);
#pragma unroll
    for (int mk = 1; mk < 16; mk <<= 1) s += __shfl_xor(s, mk, 16);
    if (sub == 0) esq[n] = s;

    // dst: unit (ntile, kb=sub>>1), inner offset ni*16 + (sub&1)*8  — layout
    // identical to r12's Bg (dist kernel is byte-compatible).
    char* outb = (char*)Bg;
    const size_t u = ((((size_t)ntile) * 8 + (sub >> 1)) << 8) + ni * 16 + (sub & 1) * 8;
    uint2 hw2 = {h01, h23}, mw2 = {m01, m23}, lw2 = {l01, l23};
    *(uint2*)(outb + u)          = hw2;               // plane h (stride 256 KB)
    *(uint2*)(outb + 262144 + u) = mw2;               // plane m
    *(uint2*)(outb + 524288 + u) = lw2;               // plane l
}

// MFMA pass: 4 mtiles x 2 ks = 8 MFMAs, literal plane indices (SROA-safe).
#define DO_PASS(APL, BPL, B)                                                 \
    _Pragma("unroll") for (int ks = 0; ks < 2; ++ks)                         \
    _Pragma("unroll") for (int mt = 0; mt < 4; ++mt)                         \
        acc[mt] = __builtin_amdgcn_mfma_f32_16x16x32_bf16(                   \
            af[APL][mt][ks], B[BPL][ks], acc[mt], 0, 0, 0);

// ds_read all 6 B-fragments of one tile into DST (register pipeline).
#define LOAD_B(DST, RB)                                                      \
    _Pragma("unroll") for (int pl = 0; pl < 3; ++pl)                         \
    _Pragma("unroll") for (int ks = 0; ks < 2; ++ks)                         \
        DST[pl][ks] = *(const bf16x8*)((RB) + pl * 8192 + ks * 1024 + lane * 16);

// Stage one 1 KB fragment-major unit of Bg into the LDS ring via DMA:
// unit u -> (plane, wn-group, ks); dest = wave-uniform base + lane*16 (HW).
__device__ __forceinline__ void stage_unit(const char* BgB, char* ringBase,
                                           int u, int it, int slotOff, int lane) {
    const int pl = u >> 3, rem = u & 7, g = rem >> 1, ks = rem & 1;
    const char* gsrc = BgB + (size_t)pl * 262144 + (size_t)(g * 32 + it) * 2048
                     + ks * 1024 + lane * 16;
    char* ldst = ringBase + slotOff + pl * 8192 + g * 2048 + ks * 1024;
    __builtin_amdgcn_global_load_lds(
        (const __attribute__((address_space(1))) void*)gsrc,
        (__attribute__((address_space(3))) void*)ldst, 16, 0, 0);
}

// Wave wn stages exactly the 6 units it will itself ds_read (g == wn), so
// its own vmcnt proves its tile landed — no visibility barrier needed.
#define STAGE6(T, SO)                                                        \
    stage_unit(BgB, ring, 0 * 8 + wn * 2 + 0, (T), (SO), lane);              \
    stage_unit(BgB, ring, 0 * 8 + wn * 2 + 1, (T), (SO), lane);              \
    stage_unit(BgB, ring, 1 * 8 + wn * 2 + 0, (T), (SO), lane);              \
    stage_unit(BgB, ring, 1 * 8 + wn * 2 + 1, (T), (SO), lane);              \
    stage_unit(BgB, ring, 2 * 8 + wn * 2 + 0, (T), (SO), lane);              \
    stage_unit(BgB, ring, 2 * 8 + wn * 2 + 1, (T), (SO), lane);

// One pipeline iteration (register-pipelined B, ONE barrier per iter):
//  - stage tile J+2 -> slot J&1 (tile J was read to regs at iter J-1; the
//    end-barrier of J-1 guarantees every wave is done with that slot)
//  - vmcnt(VM): own tile-J+1 units landed (self-staged, self-read)
//  - ds_read tile J+1 -> BNXT (no MFMA depends on it this iter)
//  - 48 MFMAs on BCUR (register-resident since iter J-1) under setprio
//  - lgkmcnt(0) + barrier: all waves done reading slot (J+1)&1 -> iter J+1
//    may re-stage it; argmin (register-only) sits after the barrier.
#define ITER(J, BCUR, BNXT, DOSTAGE, DOREAD, VM)                             \
  {                                                                          \
    if (DOSTAGE) { STAGE6((J) + 2, ((J) & 1) * 24576) }                      \
    asm volatile("s_waitcnt vmcnt(" #VM ")" ::: "memory");                   \
    if (DOREAD) {                                                            \
      const char* rb = ring + (((J) + 1) & 1) * 24576 + wn * 2048;           \
      LOAD_B(BNXT, rb)                                                       \
    }                                                                        \
    f32x4 acc[4];                                                            \
    acc[0] = f32x4{0.f, 0.f, 0.f, 0.f};                                      \
    acc[1] = f32x4{0.f, 0.f, 0.f, 0.f};                                      \
    acc[2] = f32x4{0.f, 0.f, 0.f, 0.f};                                      \
    acc[3] = f32x4{0.f, 0.f, 0.f, 0.f};                                      \
    __builtin_amdgcn_s_setprio(1);                                           \
    DO_PASS(0, 2, BCUR)                                                      \
    DO_PASS(2, 0, BCUR)                                                      \
    DO_PASS(1, 1, BCUR)                                                      \
    DO_PASS(0, 1, BCUR)                                                      \
    DO_PASS(1, 0, BCUR)                                                      \
    DO_PASS(0, 0, BCUR)                                                      \
    __builtin_amdgcn_s_setprio(0);                                           \
    asm volatile("s_waitcnt lgkmcnt(0)" ::: "memory");                       \
    __builtin_amdgcn_s_barrier();                                            \
    asm volatile("" ::: "memory");                                           \
    const int n = wn * 512 + (J) * 16 + col;                                 \
    const float e = esqS[n];                                                 \
    _Pragma("unroll") for (int mt = 0; mt < 4; ++mt)                         \
    _Pragma("unroll") for (int r = 0; r < 4; ++r) {                          \
      float d = fmaf(-2.f, acc[mt][r], e);                                   \
      if (d < best[mt][r]) { best[mt][r] = d; bidx[mt][r] = n; }             \
    }                                                                        \
  }

// ---------------------------------------------------------------------------
// Fused dist+argmin+gather v4: 256 thr = 4 waves, each wave owns ALL 64 px
// (4 mtiles) x its own 16-code column per iter. Kills the wm-pair duplicate
// B-reads (LDS reads halve), register-pipelines B (MFMAs never wait on
// ds_read), one barrier/iter, 48-MFMA phases with 4 independent acc chains.
// 512 blocks, 2 blocks/CU (LDS 56 KB; VGPR budget 256 at 8 waves/CU).
// ---------------------------------------------------------------------------
__global__ __launch_bounds__(256, 2)
void dist_fused_kernel(const float* __restrict__ laten,
                       const unsigned short* __restrict__ Bg,
                       const float* __restrict__ esq,
                       const float* __restrict__ cb,
                       float* __restrict__ out0, float* __restrict__ out1) {
    __shared__ __align__(16) char ring[49152];   // 2 x 24 KB B ring; A staging
    __shared__ float esqS[2048];                 // 8 KB

    const int tid  = threadIdx.x;
    const int lane = tid & 63;
    const int wn   = tid >> 6;                   // wave 0..3 = 512-code quarter
    const int quad = lane >> 4, col = lane & 15;
    const int bx = blockIdx.x;
    const int bb = bx >> 4, hw0 = (bx & 15) * 64;   // 64 px contiguous in hw

    const char* BgB = (const char*)Bg;

    // ---- stage A into ring slot 0 (24 KB): thread covers px p, dims 16 ----
    {
        const int p = tid & 63, dgp = tid >> 6;  // dgp 0..3 -> dg pairs
        const int mt = p >> 4, mi = p & 15;      // mtile 0..3
#pragma unroll
        for (int dd = 0; dd < 2; ++dd) {
            const int dg = dgp * 2 + dd;         // kb unit 0..7
            const float* srcA = laten + (size_t)bb * 65536 + (size_t)dg * 8192 + hw0 + p;
            alignas(16) unsigned short hv[8], mv[8], lv[8];
#pragma unroll
            for (int j = 0; j < 8; ++j) {
                float v = srcA[(size_t)j << 10]; // coalesced across p
                unsigned short h = f2bf(v);
                float r1 = v - bf2f(h);
                unsigned short m = f2bf(r1);
                unsigned short l = f2bf(r1 - bf2f(m));
                hv[j] = h; mv[j] = m; lv[j] = l;
            }
            int u = ((mt * 8 + dg) << 8) + mi * 16;
            *(uint4*)(ring + u)         = *(uint4*)hv;   // plane h (8 KB stride)
            *(uint4*)(ring + 8192 + u)  = *(uint4*)mv;   // plane m
            *(uint4*)(ring + 16384 + u) = *(uint4*)lv;   // plane l
        }
    }
    // stage e_sq (8 floats/thread, 256 threads -> 2048 floats)
    *(float4*)(esqS + tid * 8)     = *(const float4*)(esq + tid * 8);
    *(float4*)(esqS + tid * 8 + 4) = *(const float4*)(esq + tid * 8 + 4);
    __syncthreads();

    // ---- A fragments -> regs: ALL 4 mtiles per wave (96 regs resident) ----
    bf16x8 af[3][4][2];
#pragma unroll
    for (int pl = 0; pl < 3; ++pl)
#pragma unroll
        for (int mt = 0; mt < 4; ++mt)
#pragma unroll
            for (int ks = 0; ks < 2; ++ks)
                af[pl][mt][ks] = *(const bf16x8*)(ring + pl * 8192
                    + ((mt * 8 + ks * 4 + quad) << 8) + col * 16);
    __syncthreads();   // all waves done reading A before DMA clobbers slot 0

    // ---- prologue: stage tiles 0,1 (self-units); read tile 0 to regs ----
    STAGE6(0, 0)
    STAGE6(1, 24576)
    asm volatile("s_waitcnt vmcnt(6)" ::: "memory");   // own tile-0 landed
    bf16x8 bfrA[3][2], bfrB[3][2];
    LOAD_B(bfrA, ring + wn * 2048)
    asm volatile("s_waitcnt lgkmcnt(0)" ::: "memory");
    __builtin_amdgcn_s_barrier();                      // slot 0 free to re-stage
    asm volatile("" ::: "memory");

    float best[4][4];
    int   bidx[4][4];
#pragma unroll
    for (int mt = 0; mt < 4; ++mt)
#pragma unroll
        for (int r = 0; r < 4; ++r) { best[mt][r] = 3.4e38f; bidx[mt][r] = 0; }

    // ---- main pipeline: steady vmcnt(6) (6 own loads/tile, depth 2) ----
    for (int j = 0; j < 30; j += 2) {
        ITER(j,     bfrA, bfrB, true, true, 6)
        ITER(j + 1, bfrB, bfrA, true, true, 6)
    }
    ITER(30, bfrA, bfrB, false, true, 0)
    ITER(31, bfrB, bfrA, false, false, 0)

    // ---- reduce: shfl over 16 cols, then LDS over the 4 wn quarters ----
    float* redD = (float*)ring;              // [64][4]
    int*   redI = (int*)(ring + 1024);       // [64][4]
    int*   idxF = (int*)(ring + 2048);       // [64]
#pragma unroll
    for (int mt = 0; mt < 4; ++mt)
#pragma unroll
        for (int r = 0; r < 4; ++r) {
            float d = best[mt][r];
            int   i = bidx[mt][r];
#pragma unroll
            for (int m = 1; m < 16; m <<= 1) {
                float od = __shfl_xor(d, m, 16);
                int   oi = __shfl_xor(i, m, 16);
                if (od < d || (od == d && oi < i)) { d = od; i = oi; }
            }
            if (col == 0) {
                int row = mt * 16 + quad * 4 + r;     // pixel 0..63
                redD[row * 4 + wn] = d;
                redI[row * 4 + wn] = i;
            }
        }
    __syncthreads();

    if (tid < 64) {
        float bd = redD[tid * 4]; int bi = redI[tid * 4];
#pragma unroll
        for (int w = 1; w < 4; ++w) {
            float d = redD[tid * 4 + w]; int i = redI[tid * 4 + w];
            if (d < bd || (d == bd && i < bi)) { bd = d; bi = i; }
        }
        out0[bx * 64 + tid] = (float)bi;
        idxF[tid] = bi;
    }
    __syncthreads();

    // ---- fused gather: 64 px x 64 dims from the ORIGINAL fp32 codebook ----
    const int p = tid & 63, dgp = tid >> 6;          // dgp: 16 dims each
    const int idx = idxF[p];
    const float4* srcr = (const float4*)(cb + ((size_t)idx << 6) + dgp * 16);
    float* o = out1 + (size_t)bb * 65536 + (size_t)dgp * 16384 + hw0 + p;
    float4 v0 = srcr[0], v1 = srcr[1], v2 = srcr[2], v3 = srcr[3];
    o[(size_t)0  << 10] = v0.x; o[(size_t)1  << 10] = v0.y;
    o[(size_t)2  << 10] = v0.z; o[(size_t)3  << 10] = v0.w;
    o[(size_t)4  << 10] = v1.x; o[(size_t)5  << 10] = v1.y;
    o[(size_t)6  << 10] = v1.z; o[(size_t)7  << 10] = v1.w;
    o[(size_t)8  << 10] = v2.x; o[(size_t)9  << 10] = v2.y;
    o[(size_t)10 << 10] = v2.z; o[(size_t)11 << 10] = v2.w;
    o[(size_t)12 << 10] = v3.x; o[(size_t)13 << 10] = v3.y;
    o[(size_t)14 << 10] = v3.z; o[(size_t)15 << 10] = v3.w;
}

// ---------------------------------------------------------------------------
extern "C" void kernel_launch(void* const* d_in, const int* in_sizes, int n_in,
                              void* d_out, int out_size, void* d_ws, size_t ws_size,
                              hipStream_t stream) {
    const float* laten = (const float*)d_in[0];   // (32,64,32,32) fp32
    const float* cb    = (const float*)d_in[1];   // (2048,64) fp32

    float* out0 = (float*)d_out;                  // indices as float, N_PIX
    float* out1 = (float*)d_out + N_PIX;          // quant_laten, 2M

    // ws layout: esq 8 KB | Bg 768 KB   (~776 KB total)
    float* esq = (float*)d_ws;
    unsigned short* Bg = (unsigned short*)(esq + 2048);

    convert_b_kernel<<<128, 256, 0, stream>>>(cb, Bg, esq);

    dist_fused_kernel<<<512, 256, 0, stream>>>(laten, Bg, esq, cb, out0, out1);
}